// Round 1
// baseline (130.900 us; speedup 1.0000x reference)
//
#include <hip/hip_runtime.h>
#include <hip/hip_bf16.h>

#define N_TOT 4096
#define BATCH 2048
#define DIM   256
#define NCLS  100

typedef __attribute__((ext_vector_type(8))) short short8;
typedef __attribute__((ext_vector_type(4))) float floatx4;

// ---------------------------------------------------------------------------
// K1: normalize rows of concat(z_i, z_j); write fp32 + bf16 copies; extract
//     labels from one-hot; zero den accumulator.
// ---------------------------------------------------------------------------
__global__ void prep_kernel(const float* __restrict__ z_i,
                            const float* __restrict__ z_j,
                            const float* __restrict__ dist,
                            __hip_bfloat16* __restrict__ zb,
                            float* __restrict__ zf,
                            int* __restrict__ lab,
                            float* __restrict__ den)
{
    const int n = blockIdx.x;
    const int t = threadIdx.x;
    const int lane = t & 63, wv = t >> 6;

    const float* src = (n < BATCH) ? (z_i + (size_t)n * DIM)
                                   : (z_j + (size_t)(n - BATCH) * DIM);
    float v = src[t];

    float ss = v * v;
    #pragma unroll
    for (int s = 32; s; s >>= 1) ss += __shfl_xor(ss, s);

    __shared__ float wss[4];
    __shared__ int llab;
    if (lane == 0) wss[wv] = ss;
    __syncthreads();
    float tot = wss[0] + wss[1] + wss[2] + wss[3];
    float rn = 1.0f / sqrtf(tot);
    float zn = v * rn;

    zf[(size_t)n * DIM + t] = zn;
    zb[(size_t)n * DIM + t] = __float2bfloat16(zn);
    if (t == 0) den[n] = 0.0f;

    if (n < BATCH) {
        if (t < NCLS && dist[(size_t)n * NCLS + t] > 0.5f) llab = t;
        __syncthreads();
        if (t == 0) { lab[n] = llab; lab[n + BATCH] = llab; }
    }
}

// ---------------------------------------------------------------------------
// K2: exact fp32 nominator. One block per row n. Waves scan the 4096 columns
//     in 64-wide chunks; ballot finds label-matching columns; whole wave then
//     cooperatively computes each 256-long fp32 dot product. Deterministic.
// ---------------------------------------------------------------------------
__global__ void nom_kernel(const float* __restrict__ zf,
                           const int* __restrict__ lab,
                           float* __restrict__ nom)
{
    const int n = blockIdx.x;
    const int t = threadIdx.x;
    const int lane = t & 63, wv = t >> 6;

    __shared__ float zn[DIM];
    __shared__ float wsum[4];
    zn[t] = zf[(size_t)n * DIM + t];
    const int myl = lab[n];
    __syncthreads();

    float acc = 0.0f;
    for (int c = wv * 16; c < wv * 16 + 16; ++c) {
        const int m = c * 64 + lane;
        const bool pred = (lab[m] == myl) && (m != n);
        unsigned long long mask = __ballot(pred);
        while (mask) {
            const int b = __builtin_ctzll(mask);
            mask &= mask - 1;
            const int mm = c * 64 + b;
            const float* zm = zf + (size_t)mm * DIM;
            float p = zn[lane]       * zm[lane]
                    + zn[lane + 64]  * zm[lane + 64]
                    + zn[lane + 128] * zm[lane + 128]
                    + zn[lane + 192] * zm[lane + 192];
            #pragma unroll
            for (int s = 32; s; s >>= 1) p += __shfl_xor(p, s);
            acc += p;   // identical across lanes
        }
    }
    if (lane == 0) wsum[wv] = acc;
    __syncthreads();
    if (t == 0) nom[n] = wsum[0] + wsum[1] + wsum[2] + wsum[3];
}

// ---------------------------------------------------------------------------
// K3: denominator via bf16 MFMA. Block computes a 64x64 sim tile (4 waves,
//     each 32x32 as 2x2 16x16x32 frags, K-loop over 256). Epilogue: exp(),
//     zero the diagonal, reduce row-sums across the 16-lane col groups,
//     atomicAdd fp32 partials into den[row].
// ---------------------------------------------------------------------------
__global__ __launch_bounds__(256) void den_kernel(const __hip_bfloat16* __restrict__ zbp,
                                                  float* __restrict__ den)
{
    const int t = threadIdx.x;
    const int lane = t & 63, wv = t >> 6;
    const int wy = wv >> 1, wx = wv & 1;
    const int row0 = blockIdx.y * 64 + wy * 32;
    const int col0 = blockIdx.x * 64 + wx * 32;
    const int lr = lane & 15;          // row (A) / col (B) within 16-tile
    const int lk = (lane >> 4) * 8;    // k offset of this lane's 8 elements

    const short* z = (const short*)zbp;

    floatx4 acc[2][2] = {};
    for (int kk = 0; kk < DIM; kk += 32) {
        short8 a[2], b[2];
        #pragma unroll
        for (int i = 0; i < 2; ++i)
            a[i] = *(const short8*)(z + (size_t)(row0 + i * 16 + lr) * DIM + kk + lk);
        #pragma unroll
        for (int j = 0; j < 2; ++j)
            b[j] = *(const short8*)(z + (size_t)(col0 + j * 16 + lr) * DIM + kk + lk);
        #pragma unroll
        for (int i = 0; i < 2; ++i)
            #pragma unroll
            for (int j = 0; j < 2; ++j)
                acc[i][j] = __builtin_amdgcn_mfma_f32_16x16x32_bf16(a[i], b[j], acc[i][j], 0, 0, 0);
    }

    // epilogue: e = (row==col) ? 0 : exp(sim); accumulate row sums
    float rs[2][4] = {};
    #pragma unroll
    for (int i = 0; i < 2; ++i) {
        #pragma unroll
        for (int j = 0; j < 2; ++j) {
            const int gcol = col0 + j * 16 + lr;
            #pragma unroll
            for (int r = 0; r < 4; ++r) {
                const int grow = row0 + i * 16 + (lane >> 4) * 4 + r;
                const float e = (grow == gcol) ? 0.0f : __expf(acc[i][j][r]);
                rs[i][r] += e;
            }
        }
    }
    // reduce across the 16 lanes (cols) of each (lane>>4) group
    #pragma unroll
    for (int i = 0; i < 2; ++i)
        #pragma unroll
        for (int r = 0; r < 4; ++r) {
            float v = rs[i][r];
            v += __shfl_xor(v, 1);
            v += __shfl_xor(v, 2);
            v += __shfl_xor(v, 4);
            v += __shfl_xor(v, 8);
            rs[i][r] = v;
        }
    if (lr == 0) {
        #pragma unroll
        for (int i = 0; i < 2; ++i) {
            const int growb = row0 + i * 16 + (lane >> 4) * 4;
            #pragma unroll
            for (int r = 0; r < 4; ++r)
                atomicAdd(&den[growb + r], rs[i][r]);
        }
    }
}

// ---------------------------------------------------------------------------
// K4: loss = mean(nom/den) / ... = sum(nom/den) / N_TOT. Single block,
//     deterministic order.
// ---------------------------------------------------------------------------
__global__ void loss_kernel(const float* __restrict__ nom,
                            const float* __restrict__ den,
                            float* __restrict__ out)
{
    const int t = threadIdx.x;
    float s = 0.0f;
    for (int n = t; n < N_TOT; n += 256)
        s += nom[n] / den[n];
    #pragma unroll
    for (int sh = 32; sh; sh >>= 1) s += __shfl_xor(s, sh);
    __shared__ float w[4];
    if ((t & 63) == 0) w[t >> 6] = s;
    __syncthreads();
    if (t == 0) out[0] = (w[0] + w[1] + w[2] + w[3]) / (float)N_TOT;
}

// ---------------------------------------------------------------------------
extern "C" void kernel_launch(void* const* d_in, const int* in_sizes, int n_in,
                              void* d_out, int out_size, void* d_ws, size_t ws_size,
                              hipStream_t stream)
{
    const float* z_i  = (const float*)d_in[0];
    const float* z_j  = (const float*)d_in[1];
    // d_in[2] (z_n) is unused by the reference
    const float* dist = (const float*)d_in[3];

    char* ws = (char*)d_ws;
    __hip_bfloat16* zb = (__hip_bfloat16*)ws;                       // 2 MB
    float* zf  = (float*)(ws + 2u * 1024 * 1024);                   // 4 MB
    int*   lab = (int*)  (ws + 6u * 1024 * 1024);                   // 16 KB
    float* nom = (float*)(ws + 6u * 1024 * 1024 + 16 * 1024);       // 16 KB
    float* den = (float*)(ws + 6u * 1024 * 1024 + 32 * 1024);       // 16 KB

    float* out = (float*)d_out;

    hipLaunchKernelGGL(prep_kernel, dim3(N_TOT), dim3(256), 0, stream,
                       z_i, z_j, dist, zb, zf, lab, den);
    hipLaunchKernelGGL(nom_kernel, dim3(N_TOT), dim3(256), 0, stream,
                       zf, lab, nom);
    hipLaunchKernelGGL(den_kernel, dim3(64, 64), dim3(256), 0, stream,
                       zb, den);
    hipLaunchKernelGGL(loss_kernel, dim3(1), dim3(256), 0, stream,
                       nom, den, out);
}

// Round 2
// 63.985 us; speedup vs baseline: 2.0458x; 2.0458x over previous
//
#include <hip/hip_runtime.h>
#include <hip/hip_bf16.h>

#define N_TOT 4096
#define BATCH 2048
#define DIM   256
#define NCLS  100
#define NTILE 32           // 4096 / 128
#define NPAIR 528          // NTILE*(NTILE+1)/2

typedef __attribute__((ext_vector_type(8))) short short8;
typedef __attribute__((ext_vector_type(4))) float floatx4;

typedef __attribute__((address_space(1))) const unsigned int as1c_uint;
typedef __attribute__((address_space(3))) unsigned int as3_uint;

// async global->LDS, 16B per lane; lds dest is wave-uniform base (+lane*16 by HW)
__device__ __forceinline__ void gload_lds16(const void* g, void* lds_base) {
    __builtin_amdgcn_global_load_lds((as1c_uint*)g, (as3_uint*)lds_base, 16, 0, 0);
}

// ---------------------------------------------------------------------------
// K1: normalize rows of concat(z_i, z_j); write fp32 + bf16 copies; labels.
// ---------------------------------------------------------------------------
__global__ void prep_kernel(const float* __restrict__ z_i,
                            const float* __restrict__ z_j,
                            const float* __restrict__ dist,
                            __hip_bfloat16* __restrict__ zb,
                            float* __restrict__ zf,
                            int* __restrict__ lab)
{
    const int n = blockIdx.x;
    const int t = threadIdx.x;
    const int lane = t & 63, wv = t >> 6;

    const float* src = (n < BATCH) ? (z_i + (size_t)n * DIM)
                                   : (z_j + (size_t)(n - BATCH) * DIM);
    float v = src[t];

    float ss = v * v;
    #pragma unroll
    for (int s = 32; s; s >>= 1) ss += __shfl_xor(ss, s);

    __shared__ float wss[4];
    __shared__ int llab;
    if (lane == 0) wss[wv] = ss;
    __syncthreads();
    const float rn = 1.0f / sqrtf(wss[0] + wss[1] + wss[2] + wss[3]);
    const float zn = v * rn;

    zf[(size_t)n * DIM + t] = zn;
    zb[(size_t)n * DIM + t] = __float2bfloat16(zn);

    if (n < BATCH) {
        if (t < NCLS && dist[(size_t)n * NCLS + t] > 0.5f) llab = t;
        __syncthreads();
        if (t == 0) { lab[n] = llab; lab[n + BATCH] = llab; }
    }
}

// ---------------------------------------------------------------------------
// K2: class-sum partials. Block (c,s): 4 waves each scan 256 rows of the
//     s-th quarter; lane owns 4 dims. Deterministic fp32.
//     csum_part[s][c][d], s in [0,4)
// ---------------------------------------------------------------------------
__global__ void csum_kernel(const float* __restrict__ zf,
                            const int* __restrict__ lab,
                            float* __restrict__ csum_part)
{
    const int c = blockIdx.x;
    const int s = blockIdx.y;
    const int t = threadIdx.x;
    const int lane = t & 63, wv = t >> 6;
    const int m0 = s * 1024 + wv * 256;

    floatx4 acc = {0.f, 0.f, 0.f, 0.f};
    for (int m = m0; m < m0 + 256; ++m) {
        if (lab[m] == c)
            acc += *(const floatx4*)(zf + (size_t)m * DIM + lane * 4);
    }
    __shared__ float red[4][DIM];
    *(floatx4*)&red[wv][lane * 4] = acc;
    __syncthreads();
    if (t < DIM)
        csum_part[((size_t)s * NCLS + c) * DIM + t] =
            red[0][t] + red[1][t] + red[2][t] + red[3][t];
}

// ---------------------------------------------------------------------------
// K3: denominator partial sums via bf16 MFMA, symmetric-half tiling.
//     Block p -> (bi,bj), bi<=bj. 128x128 tile, LDS-staged (XOR swizzle),
//     BK=128 (two K steps). 4 waves, each 64x64 (4x4 16x16x32 frags).
//     Row sums -> den_part[bj][bi*128..]; col sums (bi!=bj) -> den_part[bi][bj*128..].
// ---------------------------------------------------------------------------
__global__ __launch_bounds__(256) void den_kernel(const __hip_bfloat16* __restrict__ zbp,
                                                  float* __restrict__ den_part)
{
    __shared__ short tileA[128 * 128];   // 32 KB, swizzled chunks of 16B
    __shared__ short tileB[128 * 128];   // 32 KB
    __shared__ float red_rs[2][128];
    __shared__ float red_cs[2][128];

    // triangular decode of (bi, bj)
    int p = blockIdx.x;
    int bi = 0;
    while (p >= NTILE - bi) { p -= NTILE - bi; ++bi; }
    const int bj = bi + p;

    const int t = threadIdx.x;
    const int lane = t & 63, wv = t >> 6;
    const int wy = wv >> 1, wx = wv & 1;
    const int lr = lane & 15;
    const int lg = lane >> 4;            // 0..3

    const short* z = (const short*)zbp;
    const int row0 = bi * 128;
    const int col0 = bj * 128;

    floatx4 acc[4][4] = {};

    for (int kt = 0; kt < 2; ++kt) {
        // ---- stage 64KB (A+B) via global_load_lds; linear LDS dest,
        //      inverse-swizzled global source (chunk ^ (row&7))
        #pragma unroll
        for (int qi = 0; qi < 8; ++qi) {
            const int q  = wv * 8 + qi;              // 0..31 -> 1KB each
            const int r  = q * 4 + lg;               // tile row of this lane
            const int cg = lr ^ (r & 7);             // global 16B-chunk index
            const short* srcA = z + (size_t)(row0 + r) * DIM + kt * 128 + cg * 8;
            gload_lds16(srcA, (char*)tileA + q * 1024);
            const short* srcB = z + (size_t)(col0 + r) * DIM + kt * 128 + cg * 8;
            gload_lds16(srcB, (char*)tileB + q * 1024);
        }
        __syncthreads();

        // ---- compute 4 k-steps of 32
        #pragma unroll
        for (int ks = 0; ks < 4; ++ks) {
            const int kc = ks * 4;                   // base 16B-chunk = kk/8
            short8 a[4], b[4];
            #pragma unroll
            for (int i = 0; i < 4; ++i) {
                const int row = wy * 64 + i * 16 + lr;
                const int ch  = (kc + lg) ^ (row & 7);
                a[i] = *(const short8*)((const char*)tileA + row * 256 + ch * 16);
            }
            #pragma unroll
            for (int j = 0; j < 4; ++j) {
                const int col = wx * 64 + j * 16 + lr;
                const int ch  = (kc + lg) ^ (col & 7);
                b[j] = *(const short8*)((const char*)tileB + col * 256 + ch * 16);
            }
            #pragma unroll
            for (int i = 0; i < 4; ++i)
                #pragma unroll
                for (int j = 0; j < 4; ++j)
                    acc[i][j] = __builtin_amdgcn_mfma_f32_16x16x32_bf16(a[i], b[j], acc[i][j], 0, 0, 0);
        }
        __syncthreads();
    }

    // ---- epilogue: e = off-diag exp(sim); accumulate row sums + col sums
    float rs[4][4] = {};       // [i][r]
    float cs[4]    = {};       // [j]
    #pragma unroll
    for (int i = 0; i < 4; ++i) {
        #pragma unroll
        for (int j = 0; j < 4; ++j) {
            const int gcol = col0 + wx * 64 + j * 16 + lr;
            #pragma unroll
            for (int r = 0; r < 4; ++r) {
                const int grow = row0 + wy * 64 + i * 16 + lg * 4 + r;
                const float e = (grow == gcol) ? 0.0f : __expf(acc[i][j][r]);
                rs[i][r] += e;
                cs[j]    += e;
            }
        }
    }
    // row sums: reduce across the 16 col-lanes of each lg group
    #pragma unroll
    for (int i = 0; i < 4; ++i)
        #pragma unroll
        for (int r = 0; r < 4; ++r) {
            float v = rs[i][r];
            v += __shfl_xor(v, 1); v += __shfl_xor(v, 2);
            v += __shfl_xor(v, 4); v += __shfl_xor(v, 8);
            rs[i][r] = v;
        }
    if (lr == 0)
        #pragma unroll
        for (int i = 0; i < 4; ++i)
            #pragma unroll
            for (int r = 0; r < 4; ++r)
                red_rs[wx][wy * 64 + i * 16 + lg * 4 + r] = rs[i][r];

    // col sums: reduce across the 4 lg row-groups
    #pragma unroll
    for (int j = 0; j < 4; ++j) {
        float v = cs[j];
        v += __shfl_xor(v, 16); v += __shfl_xor(v, 32);
        cs[j] = v;
    }
    if (lane < 16)
        #pragma unroll
        for (int j = 0; j < 4; ++j)
            red_cs[wy][wx * 64 + j * 16 + lr] = cs[j];

    __syncthreads();
    if (t < 128) {
        den_part[(size_t)bj * N_TOT + row0 + t] = red_rs[0][t] + red_rs[1][t];
        if (bi != bj)
            den_part[(size_t)bi * N_TOT + col0 + t] = red_cs[0][t] + red_cs[1][t];
    }
}

// ---------------------------------------------------------------------------
// K4: per-row finalize: nom = z_n . csum[lab[n]] - 1 ; den = sum of 32 partials;
//     block partial of sum(nom/den). One wave per row, 8 rows/block.
// ---------------------------------------------------------------------------
__global__ __launch_bounds__(512) void rowfinal_kernel(const float* __restrict__ zf,
                                                       const int* __restrict__ lab,
                                                       const float* __restrict__ csum_part,
                                                       const float* __restrict__ den_part,
                                                       float* __restrict__ partial)
{
    const int t = threadIdx.x;
    const int lane = t & 63, wv = t >> 6;
    const int n = blockIdx.x * 8 + wv;
    const int c = lab[n];

    const floatx4 zv = *(const floatx4*)(zf + (size_t)n * DIM + lane * 4);
    floatx4 sv = {0.f, 0.f, 0.f, 0.f};
    #pragma unroll
    for (int s = 0; s < 4; ++s)
        sv += *(const floatx4*)(csum_part + ((size_t)s * NCLS + c) * DIM + lane * 4);

    float pd = zv[0] * sv[0] + zv[1] * sv[1] + zv[2] * sv[2] + zv[3] * sv[3];
    float dd = (lane < 32) ? den_part[(size_t)lane * N_TOT + n] : 0.0f;
    #pragma unroll
    for (int sh = 32; sh; sh >>= 1) {
        pd += __shfl_xor(pd, sh);
        dd += __shfl_xor(dd, sh);
    }

    __shared__ float w[8];
    if (lane == 0) w[wv] = (pd - 1.0f) / dd;
    __syncthreads();
    if (t == 0) {
        float ssum = 0.f;
        #pragma unroll
        for (int i = 0; i < 8; ++i) ssum += w[i];
        partial[blockIdx.x] = ssum;
    }
}

// ---------------------------------------------------------------------------
// K5: final reduce of 512 block partials; loss = sum / N_TOT.
// ---------------------------------------------------------------------------
__global__ void loss_kernel(const float* __restrict__ partial,
                            float* __restrict__ out)
{
    const int t = threadIdx.x;      // 512 threads
    float s = partial[t];
    #pragma unroll
    for (int sh = 32; sh; sh >>= 1) s += __shfl_xor(s, sh);
    __shared__ float w[8];
    if ((t & 63) == 0) w[t >> 6] = s;
    __syncthreads();
    if (t == 0) {
        float tot = 0.f;
        #pragma unroll
        for (int i = 0; i < 8; ++i) tot += w[i];
        out[0] = tot / (float)N_TOT;
    }
}

// ---------------------------------------------------------------------------
extern "C" void kernel_launch(void* const* d_in, const int* in_sizes, int n_in,
                              void* d_out, int out_size, void* d_ws, size_t ws_size,
                              hipStream_t stream)
{
    const float* z_i  = (const float*)d_in[0];
    const float* z_j  = (const float*)d_in[1];
    // d_in[2] (z_n) unused by the reference
    const float* dist = (const float*)d_in[3];

    char* ws = (char*)d_ws;
    __hip_bfloat16* zb = (__hip_bfloat16*)ws;                                   // 2 MB
    float* zf        = (float*)(ws + 2u * 1024 * 1024);                         // 4 MB
    int*   lab       = (int*)  (ws + 6u * 1024 * 1024);                         // 16 KB
    float* csum_part = (float*)(ws + 6u * 1024 * 1024 + 16 * 1024);             // 400 KB
    float* den_part  = (float*)(ws + 6u * 1024 * 1024 + 416 * 1024);            // 512 KB
    float* partial   = (float*)(ws + 6u * 1024 * 1024 + 928 * 1024);            // 2 KB

    float* out = (float*)d_out;

    hipLaunchKernelGGL(prep_kernel, dim3(N_TOT), dim3(256), 0, stream,
                       z_i, z_j, dist, zb, zf, lab);
    hipLaunchKernelGGL(csum_kernel, dim3(NCLS, 4), dim3(256), 0, stream,
                       zf, lab, csum_part);
    hipLaunchKernelGGL(den_kernel, dim3(NPAIR), dim3(256), 0, stream,
                       zb, den_part);
    hipLaunchKernelGGL(rowfinal_kernel, dim3(N_TOT / 8), dim3(512), 0, stream,
                       zf, lab, csum_part, den_part, partial);
    hipLaunchKernelGGL(loss_kernel, dim3(1), dim3(512), 0, stream,
                       partial, out);
}

// Round 4
// 60.884 us; speedup vs baseline: 2.1500x; 1.0509x over previous
//
#include <hip/hip_runtime.h>
#include <hip/hip_bf16.h>

#define N_TOT 4096
#define BATCH 2048
#define DIM   256
#define NCLS  100
#define NSLC  4            // csum slices
#define NTILE 32           // 4096 / 128
#define NPAIR 528          // NTILE*(NTILE+1)/2

typedef __attribute__((ext_vector_type(8))) short short8;
typedef __attribute__((ext_vector_type(4))) float floatx4;
typedef __attribute__((ext_vector_type(4))) unsigned short ushortx4;

typedef __attribute__((address_space(1))) const unsigned int as1c_uint;
typedef __attribute__((address_space(3))) unsigned int as3_uint;

// async global->LDS, 16B per lane; lds dest is wave-uniform base (+lane*16 by HW)
__device__ __forceinline__ void gload_lds16(const void* g, void* lds_base) {
    __builtin_amdgcn_global_load_lds((as1c_uint*)g, (as3_uint*)lds_base, 16, 0, 0);
}

__device__ __forceinline__ unsigned short f2bf(float x) {
    __hip_bfloat16 h = __float2bfloat16(x);
    return *(unsigned short*)&h;
}

// ---------------------------------------------------------------------------
// K1: normalize rows of concat(z_i, z_j). Wave-per-row, no barriers.
//     Writes bf16 + fp32 copies; extracts labels via ballot.
// ---------------------------------------------------------------------------
__global__ __launch_bounds__(256) void prep_kernel(const float* __restrict__ z_i,
                                                   const float* __restrict__ z_j,
                                                   const float* __restrict__ dist,
                                                   unsigned short* __restrict__ zb,
                                                   float* __restrict__ zf,
                                                   int* __restrict__ lab)
{
    const int t = threadIdx.x;
    const int lane = t & 63, wv = t >> 6;

    #pragma unroll
    for (int it = 0; it < 2; ++it) {
        const int n = blockIdx.x * 8 + it * 4 + wv;
        const float* src = (n < BATCH) ? (z_i + (size_t)n * DIM)
                                       : (z_j + (size_t)(n - BATCH) * DIM);
        const floatx4 v = *(const floatx4*)(src + lane * 4);
        float ss = v[0]*v[0] + v[1]*v[1] + v[2]*v[2] + v[3]*v[3];
        #pragma unroll
        for (int s = 32; s; s >>= 1) ss += __shfl_xor(ss, s);
        const float rn = 1.0f / sqrtf(ss);

        floatx4 zn;
        zn[0] = v[0]*rn; zn[1] = v[1]*rn; zn[2] = v[2]*rn; zn[3] = v[3]*rn;
        *(floatx4*)(zf + (size_t)n * DIM + lane * 4) = zn;
        ushortx4 zp;
        zp[0] = f2bf(zn[0]); zp[1] = f2bf(zn[1]);
        zp[2] = f2bf(zn[2]); zp[3] = f2bf(zn[3]);
        *(ushortx4*)(zb + (size_t)n * DIM + lane * 4) = zp;

        if (n < BATCH) {
            float d0 = 0.f, d1 = 0.f;
            if (lane < 50) {
                d0 = dist[(size_t)n * NCLS + 2 * lane];
                d1 = dist[(size_t)n * NCLS + 2 * lane + 1];
            }
            const unsigned long long m0 = __ballot(d0 > 0.5f);
            const unsigned long long m1 = __ballot(d1 > 0.5f);
            if (lane == 0) {
                const int l = m0 ? 2 * __builtin_ctzll(m0)
                                 : 2 * __builtin_ctzll(m1) + 1;
                lab[n] = l;
                lab[n + BATCH] = l;
            }
        }
    }
}

// ---------------------------------------------------------------------------
// K2: class-sum partials. Block (c,s): 4 waves each scan 256 rows of the
//     s-th quarter; lane owns 4 dims. Deterministic fp32.
// ---------------------------------------------------------------------------
__global__ __launch_bounds__(256) void csum_kernel(const float* __restrict__ zf,
                                                   const int* __restrict__ lab,
                                                   float* __restrict__ csum_part)
{
    const int c = blockIdx.x;
    const int s = blockIdx.y;
    const int t = threadIdx.x;
    const int lane = t & 63, wv = t >> 6;
    const int m0 = s * 1024 + wv * 256;

    floatx4 acc = {0.f, 0.f, 0.f, 0.f};
    for (int m = m0; m < m0 + 256; ++m) {
        if (lab[m] == c)
            acc += *(const floatx4*)(zf + (size_t)m * DIM + lane * 4);
    }
    __shared__ float red[4][DIM];
    *(floatx4*)&red[wv][lane * 4] = acc;
    __syncthreads();
    if (t < DIM)
        csum_part[((size_t)s * NCLS + c) * DIM + t] =
            red[0][t] + red[1][t] + red[2][t] + red[3][t];
}

// ---------------------------------------------------------------------------
// K3: denominator partials via bf16 MFMA, symmetric-half tiling, BK=64
//     double-buffered LDS (stage next K-tile before computing current).
// ---------------------------------------------------------------------------
__global__ __launch_bounds__(256) void den_kernel(const __hip_bfloat16* __restrict__ zbp,
                                                  float* __restrict__ den_part)
{
    __shared__ short tA[2][128 * 64];    // 2 x 16 KB
    __shared__ short tB[2][128 * 64];    // 2 x 16 KB
    __shared__ float red_rs[2][128];
    __shared__ float red_cs[2][128];

    int p = blockIdx.x;
    int bi = 0;
    while (p >= NTILE - bi) { p -= NTILE - bi; ++bi; }
    const int bj = bi + p;

    const int t = threadIdx.x;
    const int lane = t & 63, wv = t >> 6;
    const int wy = wv >> 1, wx = wv & 1;
    const int lr = lane & 15;
    const int lg = lane >> 4;            // 0..3
    const int sr = lane >> 3;            // 0..7 row-in-group for staging
    const int sc = lane & 7;             // chunk base for staging

    const short* z = (const short*)zbp;
    const int row0 = bi * 128;
    const int col0 = bj * 128;

    floatx4 acc[4][4] = {};

    auto STAGE = [&](int kt, int b) {
        #pragma unroll
        for (int q2 = 0; q2 < 4; ++q2) {
            const int q = wv * 4 + q2;               // 0..15, 1 KB each
            const int r = q * 8 + sr;
            const int cg = sc ^ (r & 7);
            gload_lds16(z + (size_t)(row0 + r) * DIM + kt * 64 + cg * 8,
                        (char*)tA[b] + q * 1024);
            gload_lds16(z + (size_t)(col0 + r) * DIM + kt * 64 + cg * 8,
                        (char*)tB[b] + q * 1024);
        }
    };
    auto COMPUTE = [&](int b) {
        #pragma unroll
        for (int ks = 0; ks < 2; ++ks) {
            short8 a[4], bb[4];
            #pragma unroll
            for (int i = 0; i < 4; ++i) {
                const int row = wy * 64 + i * 16 + lr;
                const int ch  = ((ks << 2) + lg) ^ (row & 7);
                a[i] = *(const short8*)((const char*)tA[b] + row * 128 + ch * 16);
            }
            #pragma unroll
            for (int j = 0; j < 4; ++j) {
                const int col = wx * 64 + j * 16 + lr;
                const int ch  = ((ks << 2) + lg) ^ (col & 7);
                bb[j] = *(const short8*)((const char*)tB[b] + col * 128 + ch * 16);
            }
            #pragma unroll
            for (int i = 0; i < 4; ++i)
                #pragma unroll
                for (int j = 0; j < 4; ++j)
                    acc[i][j] = __builtin_amdgcn_mfma_f32_16x16x32_bf16(a[i], bb[j], acc[i][j], 0, 0, 0);
        }
    };

    STAGE(0, 0);
    __syncthreads();
    int cur = 0;
    #pragma unroll
    for (int kt = 0; kt < 4; ++kt) {
        if (kt < 3) STAGE(kt + 1, cur ^ 1);
        COMPUTE(cur);
        __syncthreads();
        cur ^= 1;
    }

    // ---- epilogue: e = off-diag exp(sim); row sums + col sums
    float rs[4][4] = {};
    float cs[4]    = {};
    #pragma unroll
    for (int i = 0; i < 4; ++i) {
        #pragma unroll
        for (int j = 0; j < 4; ++j) {
            const int gcol = col0 + wx * 64 + j * 16 + lr;
            #pragma unroll
            for (int r = 0; r < 4; ++r) {
                const int grow = row0 + wy * 64 + i * 16 + lg * 4 + r;
                const float e = (grow == gcol) ? 0.0f : __expf(acc[i][j][r]);
                rs[i][r] += e;
                cs[j]    += e;
            }
        }
    }
    #pragma unroll
    for (int i = 0; i < 4; ++i)
        #pragma unroll
        for (int r = 0; r < 4; ++r) {
            float v = rs[i][r];
            v += __shfl_xor(v, 1); v += __shfl_xor(v, 2);
            v += __shfl_xor(v, 4); v += __shfl_xor(v, 8);
            rs[i][r] = v;
        }
    if (lr == 0)
        #pragma unroll
        for (int i = 0; i < 4; ++i)
            #pragma unroll
            for (int r = 0; r < 4; ++r)
                red_rs[wx][wy * 64 + i * 16 + lg * 4 + r] = rs[i][r];

    #pragma unroll
    for (int j = 0; j < 4; ++j) {
        float v = cs[j];
        v += __shfl_xor(v, 16); v += __shfl_xor(v, 32);
        cs[j] = v;
    }
    if (lane < 16)
        #pragma unroll
        for (int j = 0; j < 4; ++j)
            red_cs[wy][wx * 64 + j * 16 + lr] = cs[j];

    __syncthreads();
    if (t < 128) {
        den_part[(size_t)bj * N_TOT + row0 + t] = red_rs[0][t] + red_rs[1][t];
        if (bi != bj)
            den_part[(size_t)bi * N_TOT + col0 + t] = red_cs[0][t] + red_cs[1][t];
    }
}

// ---------------------------------------------------------------------------
// K4: per-row finalize: nom = zf[n] . csum[lab[n]] - 1; den = sum of 32
//     partials; block partial of sum(nom/den). 2 rows per wave.
// ---------------------------------------------------------------------------
__global__ __launch_bounds__(256) void rowfinal_kernel(const float* __restrict__ zf,
                                                       const int* __restrict__ lab,
                                                       const float* __restrict__ csum_part,
                                                       const float* __restrict__ den_part,
                                                       float* __restrict__ partial)
{
    const int t = threadIdx.x;
    const int lane = t & 63, wv = t >> 6;

    float bsum = 0.0f;
    #pragma unroll
    for (int it = 0; it < 2; ++it) {
        const int n = blockIdx.x * 8 + it * 4 + wv;
        const int c = lab[n];

        const floatx4 zv = *(const floatx4*)(zf + (size_t)n * DIM + lane * 4);
        floatx4 sv = {0.f, 0.f, 0.f, 0.f};
        #pragma unroll
        for (int s = 0; s < NSLC; ++s)
            sv += *(const floatx4*)(csum_part + ((size_t)s * NCLS + c) * DIM + lane * 4);

        float pd = zv[0]*sv[0] + zv[1]*sv[1] + zv[2]*sv[2] + zv[3]*sv[3];
        float dd = (lane < 32) ? den_part[(size_t)lane * N_TOT + n] : 0.0f;
        #pragma unroll
        for (int sh = 32; sh; sh >>= 1) {
            pd += __shfl_xor(pd, sh);
            dd += __shfl_xor(dd, sh);
        }
        bsum += (pd - 1.0f) / dd;
    }

    __shared__ float w[4];
    if (lane == 0) w[wv] = bsum;
    __syncthreads();
    if (t == 0)
        partial[blockIdx.x] = w[0] + w[1] + w[2] + w[3];
}

// ---------------------------------------------------------------------------
// K5: final reduce of 512 block partials; loss = sum / N_TOT.
// ---------------------------------------------------------------------------
__global__ __launch_bounds__(512) void loss_kernel(const float* __restrict__ partial,
                                                   float* __restrict__ out)
{
    const int t = threadIdx.x;
    float s = partial[t];
    #pragma unroll
    for (int sh = 32; sh; sh >>= 1) s += __shfl_xor(s, sh);
    __shared__ float w[8];
    if ((t & 63) == 0) w[t >> 6] = s;
    __syncthreads();
    if (t == 0) {
        float tot = 0.f;
        #pragma unroll
        for (int i = 0; i < 8; ++i) tot += w[i];
        out[0] = tot / (float)N_TOT;
    }
}

// ---------------------------------------------------------------------------
extern "C" void kernel_launch(void* const* d_in, const int* in_sizes, int n_in,
                              void* d_out, int out_size, void* d_ws, size_t ws_size,
                              hipStream_t stream)
{
    const float* z_i  = (const float*)d_in[0];
    const float* z_j  = (const float*)d_in[1];
    // d_in[2] (z_n) unused by the reference
    const float* dist = (const float*)d_in[3];

    char* ws = (char*)d_ws;
    unsigned short* zb = (unsigned short*)ws;                                   // 2 MB
    float* zf        = (float*)(ws + 2u * 1024 * 1024);                         // 4 MB
    int*   lab       = (int*)  (ws + 6u * 1024 * 1024);                         // 16 KB
    float* csum_part = (float*)(ws + 6u * 1024 * 1024 + 16 * 1024);             // 400 KB
    float* den_part  = (float*)(ws + 6u * 1024 * 1024 + 416 * 1024);            // 512 KB
    float* partial   = (float*)(ws + 6u * 1024 * 1024 + 928 * 1024);            // 2 KB

    float* out = (float*)d_out;

    hipLaunchKernelGGL(prep_kernel, dim3(512), dim3(256), 0, stream,
                       z_i, z_j, dist, zb, zf, lab);
    hipLaunchKernelGGL(csum_kernel, dim3(NCLS, NSLC), dim3(256), 0, stream,
                       zf, lab, csum_part);
    hipLaunchKernelGGL(den_kernel, dim3(NPAIR), dim3(256), 0, stream,
                       (const __hip_bfloat16*)zb, den_part);
    hipLaunchKernelGGL(rowfinal_kernel, dim3(N_TOT / 8), dim3(256), 0, stream,
                       zf, lab, csum_part, den_part, partial);
    hipLaunchKernelGGL(loss_kernel, dim3(1), dim3(512), 0, stream,
                       partial, out);
}

// Round 5
// 39.655 us; speedup vs baseline: 3.3010x; 1.5353x over previous
//
#include <hip/hip_runtime.h>
#include <hip/hip_bf16.h>

#define N_TOT 4096
#define BATCH 2048
#define DIM   256
#define NCLS  100
#define NSLC  4            // csum slices
#define NTILE 32           // 4096 / 128
#define NPAIR 528          // NTILE*(NTILE+1)/2
#define NWORK (NPAIR + NCLS * NSLC)   // 928 blocks in fused work kernel

typedef __attribute__((ext_vector_type(8))) short short8;
typedef __attribute__((ext_vector_type(4))) float floatx4;
typedef __attribute__((ext_vector_type(4))) unsigned short ushortx4;

typedef __attribute__((address_space(1))) const unsigned int as1c_uint;
typedef __attribute__((address_space(3))) unsigned int as3_uint;

// async global->LDS, 16B per lane; lds dest is wave-uniform base (+lane*16 by HW)
__device__ __forceinline__ void gload_lds16(const void* g, void* lds_base) {
    __builtin_amdgcn_global_load_lds((as1c_uint*)g, (as3_uint*)lds_base, 16, 0, 0);
}

__device__ __forceinline__ unsigned short f2bf(float x) {
    __hip_bfloat16 h = __float2bfloat16(x);
    return *(unsigned short*)&h;
}

// ---------------------------------------------------------------------------
// K1: normalize rows of concat(z_i, z_j). Wave-per-row, no barriers.
//     Writes bf16 + fp32 copies; extracts labels via ballot; zeros the
//     last-block counter used by K3.
// ---------------------------------------------------------------------------
__global__ __launch_bounds__(256) void prep_kernel(const float* __restrict__ z_i,
                                                   const float* __restrict__ z_j,
                                                   const float* __restrict__ dist,
                                                   unsigned short* __restrict__ zb,
                                                   float* __restrict__ zf,
                                                   int* __restrict__ lab,
                                                   int* __restrict__ counter)
{
    const int t = threadIdx.x;
    const int lane = t & 63, wv = t >> 6;
    if (blockIdx.x == 0 && t == 0) *counter = 0;

    #pragma unroll
    for (int it = 0; it < 2; ++it) {
        const int n = blockIdx.x * 8 + it * 4 + wv;
        const float* src = (n < BATCH) ? (z_i + (size_t)n * DIM)
                                       : (z_j + (size_t)(n - BATCH) * DIM);
        const floatx4 v = *(const floatx4*)(src + lane * 4);
        float ss = v[0]*v[0] + v[1]*v[1] + v[2]*v[2] + v[3]*v[3];
        #pragma unroll
        for (int s = 32; s; s >>= 1) ss += __shfl_xor(ss, s);
        const float rn = 1.0f / sqrtf(ss);

        floatx4 zn;
        zn[0] = v[0]*rn; zn[1] = v[1]*rn; zn[2] = v[2]*rn; zn[3] = v[3]*rn;
        *(floatx4*)(zf + (size_t)n * DIM + lane * 4) = zn;
        ushortx4 zp;
        zp[0] = f2bf(zn[0]); zp[1] = f2bf(zn[1]);
        zp[2] = f2bf(zn[2]); zp[3] = f2bf(zn[3]);
        *(ushortx4*)(zb + (size_t)n * DIM + lane * 4) = zp;

        if (n < BATCH) {
            float d0 = 0.f, d1 = 0.f;
            if (lane < 50) {
                d0 = dist[(size_t)n * NCLS + 2 * lane];
                d1 = dist[(size_t)n * NCLS + 2 * lane + 1];
            }
            const unsigned long long m0 = __ballot(d0 > 0.5f);
            const unsigned long long m1 = __ballot(d1 > 0.5f);
            if (lane == 0) {
                const int l = m0 ? 2 * __builtin_ctzll(m0)
                                 : 2 * __builtin_ctzll(m1) + 1;
                lab[n] = l;
                lab[n + BATCH] = l;
            }
        }
    }
}

// ---------------------------------------------------------------------------
// K2 (fused): blocks [0,NPAIR) = den MFMA tiles; [NPAIR,NWORK) = class sums.
//     Both depend only on prep; csum blocks run under den's tail.
// ---------------------------------------------------------------------------
__global__ __launch_bounds__(256) void work_kernel(const __hip_bfloat16* __restrict__ zbp,
                                                   const float* __restrict__ zf,
                                                   const int* __restrict__ lab,
                                                   float* __restrict__ den_part,
                                                   float* __restrict__ csum_part)
{
    __shared__ short tA[2][128 * 64];    // 2 x 16 KB
    __shared__ short tB[2][128 * 64];    // 2 x 16 KB
    __shared__ float red_rs[2][128];
    __shared__ float red_cs[2][128];
    __shared__ float cred[4][DIM];       // csum reduction

    const int t = threadIdx.x;
    const int lane = t & 63, wv = t >> 6;

    if (blockIdx.x >= NPAIR) {
        // ---------------- csum path ----------------
        const int b = blockIdx.x - NPAIR;          // 0..399
        const int c = b % NCLS;
        const int s = b / NCLS;
        const int m0 = s * 1024 + wv * 256;

        floatx4 acc = {0.f, 0.f, 0.f, 0.f};
        #pragma unroll
        for (int g = 0; g < 4; ++g) {
            const int m = m0 + g * 64 + lane;
            unsigned long long mask = __ballot(lab[m] == c);
            while (mask) {
                const int bit = __builtin_ctzll(mask);
                mask &= mask - 1;
                const int mm = m0 + g * 64 + bit;
                acc += *(const floatx4*)(zf + (size_t)mm * DIM + lane * 4);
            }
        }
        *(floatx4*)&cred[wv][lane * 4] = acc;
        __syncthreads();
        if (t < DIM)
            csum_part[((size_t)s * NCLS + c) * DIM + t] =
                cred[0][t] + cred[1][t] + cred[2][t] + cred[3][t];
        return;
    }

    // ---------------- den path ----------------
    int p = blockIdx.x;
    int bi = 0;
    while (p >= NTILE - bi) { p -= NTILE - bi; ++bi; }
    const int bj = bi + p;

    const int wy = wv >> 1, wx = wv & 1;
    const int lr = lane & 15;
    const int lg = lane >> 4;            // 0..3
    const int sr = lane >> 3;            // 0..7 row-in-group for staging
    const int sc = lane & 7;             // chunk base for staging

    const short* z = (const short*)zbp;
    const int row0 = bi * 128;
    const int col0 = bj * 128;

    floatx4 acc[4][4] = {};

    auto STAGE = [&](int kt, int b) {
        #pragma unroll
        for (int q2 = 0; q2 < 4; ++q2) {
            const int q = wv * 4 + q2;               // 0..15, 1 KB each
            const int r = q * 8 + sr;
            const int cg = sc ^ (r & 7);
            gload_lds16(z + (size_t)(row0 + r) * DIM + kt * 64 + cg * 8,
                        (char*)tA[b] + q * 1024);
            gload_lds16(z + (size_t)(col0 + r) * DIM + kt * 64 + cg * 8,
                        (char*)tB[b] + q * 1024);
        }
    };
    auto COMPUTE = [&](int b) {
        #pragma unroll
        for (int ks = 0; ks < 2; ++ks) {
            short8 a[4], bb[4];
            #pragma unroll
            for (int i = 0; i < 4; ++i) {
                const int row = wy * 64 + i * 16 + lr;
                const int ch  = ((ks << 2) + lg) ^ (row & 7);
                a[i] = *(const short8*)((const char*)tA[b] + row * 128 + ch * 16);
            }
            #pragma unroll
            for (int j = 0; j < 4; ++j) {
                const int col = wx * 64 + j * 16 + lr;
                const int ch  = ((ks << 2) + lg) ^ (col & 7);
                bb[j] = *(const short8*)((const char*)tB[b] + col * 128 + ch * 16);
            }
            #pragma unroll
            for (int i = 0; i < 4; ++i)
                #pragma unroll
                for (int j = 0; j < 4; ++j)
                    acc[i][j] = __builtin_amdgcn_mfma_f32_16x16x32_bf16(a[i], bb[j], acc[i][j], 0, 0, 0);
        }
    };

    STAGE(0, 0);
    __syncthreads();
    int cur = 0;
    #pragma unroll
    for (int kt = 0; kt < 4; ++kt) {
        if (kt < 3) STAGE(kt + 1, cur ^ 1);
        COMPUTE(cur);
        __syncthreads();
        cur ^= 1;
    }

    // ---- epilogue: e = off-diag exp(sim); row sums + col sums
    float rs[4][4] = {};
    float cs[4]    = {};
    #pragma unroll
    for (int i = 0; i < 4; ++i) {
        #pragma unroll
        for (int j = 0; j < 4; ++j) {
            const int gcol = col0 + wx * 64 + j * 16 + lr;
            #pragma unroll
            for (int r = 0; r < 4; ++r) {
                const int grow = row0 + wy * 64 + i * 16 + lg * 4 + r;
                const float e = (grow == gcol) ? 0.0f : __expf(acc[i][j][r]);
                rs[i][r] += e;
                cs[j]    += e;
            }
        }
    }
    #pragma unroll
    for (int i = 0; i < 4; ++i)
        #pragma unroll
        for (int r = 0; r < 4; ++r) {
            float v = rs[i][r];
            v += __shfl_xor(v, 1); v += __shfl_xor(v, 2);
            v += __shfl_xor(v, 4); v += __shfl_xor(v, 8);
            rs[i][r] = v;
        }
    if (lr == 0)
        #pragma unroll
        for (int i = 0; i < 4; ++i)
            #pragma unroll
            for (int r = 0; r < 4; ++r)
                red_rs[wx][wy * 64 + i * 16 + lg * 4 + r] = rs[i][r];

    #pragma unroll
    for (int j = 0; j < 4; ++j) {
        float v = cs[j];
        v += __shfl_xor(v, 16); v += __shfl_xor(v, 32);
        cs[j] = v;
    }
    if (lane < 16)
        #pragma unroll
        for (int j = 0; j < 4; ++j)
            red_cs[wy][wx * 64 + j * 16 + lr] = cs[j];

    __syncthreads();
    if (t < 128) {
        den_part[(size_t)bj * N_TOT + row0 + t] = red_rs[0][t] + red_rs[1][t];
        if (bi != bj)
            den_part[(size_t)bi * N_TOT + col0 + t] = red_cs[0][t] + red_cs[1][t];
    }
}

// ---------------------------------------------------------------------------
// K3: per-row finalize + last-block final reduce (deterministic order).
//     nom = zf[n].csum[lab[n]] - 1; den = sum of 32 partials.
// ---------------------------------------------------------------------------
__global__ __launch_bounds__(256) void final_kernel(const float* __restrict__ zf,
                                                    const int* __restrict__ lab,
                                                    const float* __restrict__ csum_part,
                                                    const float* __restrict__ den_part,
                                                    float* __restrict__ partial,
                                                    int* __restrict__ counter,
                                                    float* __restrict__ out)
{
    const int t = threadIdx.x;
    const int lane = t & 63, wv = t >> 6;

    float bsum = 0.0f;
    #pragma unroll
    for (int it = 0; it < 2; ++it) {
        const int n = blockIdx.x * 8 + it * 4 + wv;
        const int c = lab[n];

        const floatx4 zv = *(const floatx4*)(zf + (size_t)n * DIM + lane * 4);
        floatx4 sv = {0.f, 0.f, 0.f, 0.f};
        #pragma unroll
        for (int s = 0; s < NSLC; ++s)
            sv += *(const floatx4*)(csum_part + ((size_t)s * NCLS + c) * DIM + lane * 4);

        float pd = zv[0]*sv[0] + zv[1]*sv[1] + zv[2]*sv[2] + zv[3]*sv[3];
        float dd = (lane < 32) ? den_part[(size_t)lane * N_TOT + n] : 0.0f;
        #pragma unroll
        for (int sh = 32; sh; sh >>= 1) {
            pd += __shfl_xor(pd, sh);
            dd += __shfl_xor(dd, sh);
        }
        bsum += (pd - 1.0f) / dd;
    }

    __shared__ float w[4];
    __shared__ int amlast;
    if (lane == 0) w[wv] = bsum;
    __syncthreads();
    if (t == 0) {
        partial[blockIdx.x] = w[0] + w[1] + w[2] + w[3];
        __threadfence();
        amlast = (atomicAdd(counter, 1) == (int)gridDim.x - 1);
    }
    __syncthreads();
    if (amlast) {
        __threadfence();
        float s = partial[t] + partial[t + 256];
        #pragma unroll
        for (int sh = 32; sh; sh >>= 1) s += __shfl_xor(s, sh);
        if (lane == 0) w[wv] = s;
        __syncthreads();
        if (t == 0)
            out[0] = (w[0] + w[1] + w[2] + w[3]) / (float)N_TOT;
    }
}

// ---------------------------------------------------------------------------
extern "C" void kernel_launch(void* const* d_in, const int* in_sizes, int n_in,
                              void* d_out, int out_size, void* d_ws, size_t ws_size,
                              hipStream_t stream)
{
    const float* z_i  = (const float*)d_in[0];
    const float* z_j  = (const float*)d_in[1];
    // d_in[2] (z_n) unused by the reference
    const float* dist = (const float*)d_in[3];

    char* ws = (char*)d_ws;
    unsigned short* zb = (unsigned short*)ws;                                   // 2 MB
    float* zf        = (float*)(ws + 2u * 1024 * 1024);                         // 4 MB
    int*   lab       = (int*)  (ws + 6u * 1024 * 1024);                         // 16 KB
    float* csum_part = (float*)(ws + 6u * 1024 * 1024 + 16 * 1024);             // 400 KB
    float* den_part  = (float*)(ws + 6u * 1024 * 1024 + 416 * 1024);            // 512 KB
    float* partial   = (float*)(ws + 6u * 1024 * 1024 + 928 * 1024);            // 2 KB
    int*   counter   = (int*)  (ws + 6u * 1024 * 1024 + 930 * 1024);            // 4 B

    float* out = (float*)d_out;

    hipLaunchKernelGGL(prep_kernel, dim3(512), dim3(256), 0, stream,
                       z_i, z_j, dist, zb, zf, lab, counter);
    hipLaunchKernelGGL(work_kernel, dim3(NWORK), dim3(256), 0, stream,
                       (const __hip_bfloat16*)zb, zf, lab, den_part, csum_part);
    hipLaunchKernelGGL(final_kernel, dim3(N_TOT / 8), dim3(256), 0, stream,
                       zf, lab, csum_part, den_part, partial, counter, out);
}

// Round 6
// 37.344 us; speedup vs baseline: 3.5053x; 1.0619x over previous
//
#include <hip/hip_runtime.h>
#include <hip/hip_bf16.h>

#define N_TOT 4096
#define BATCH 2048
#define DIM   256
#define NCLS  100
#define NSLC  4            // csum slices
#define NTILE 32           // 4096 / 128
#define NPAIR 528          // NTILE*(NTILE+1)/2
#define NWORK (NPAIR + NCLS * NSLC)   // 928 blocks in fused work kernel

typedef __attribute__((ext_vector_type(8))) short short8;
typedef __attribute__((ext_vector_type(4))) float floatx4;
typedef __attribute__((ext_vector_type(4))) unsigned short ushortx4;

typedef __attribute__((address_space(1))) const unsigned int as1c_uint;
typedef __attribute__((address_space(3))) unsigned int as3_uint;

// async global->LDS, 16B per lane; lds dest is wave-uniform base (+lane*16 by HW)
__device__ __forceinline__ void gload_lds16(const void* g, void* lds_base) {
    __builtin_amdgcn_global_load_lds((as1c_uint*)g, (as3_uint*)lds_base, 16, 0, 0);
}

__device__ __forceinline__ unsigned short f2bf(float x) {
    __hip_bfloat16 h = __float2bfloat16(x);
    return *(unsigned short*)&h;
}

// ---------------------------------------------------------------------------
// K1: normalize rows of concat(z_i, z_j). Wave-per-row, no barriers.
//     Writes bf16 + fp32 copies; extracts labels via ballot; zeros the
//     last-block counter used by K3.
// ---------------------------------------------------------------------------
__global__ __launch_bounds__(256) void prep_kernel(const float* __restrict__ z_i,
                                                   const float* __restrict__ z_j,
                                                   const float* __restrict__ dist,
                                                   unsigned short* __restrict__ zb,
                                                   float* __restrict__ zf,
                                                   int* __restrict__ lab,
                                                   int* __restrict__ counter)
{
    const int t = threadIdx.x;
    const int lane = t & 63, wv = t >> 6;
    if (blockIdx.x == 0 && t == 0) *counter = 0;

    #pragma unroll
    for (int it = 0; it < 2; ++it) {
        const int n = blockIdx.x * 8 + it * 4 + wv;
        const float* src = (n < BATCH) ? (z_i + (size_t)n * DIM)
                                       : (z_j + (size_t)(n - BATCH) * DIM);
        const floatx4 v = *(const floatx4*)(src + lane * 4);
        float ss = v[0]*v[0] + v[1]*v[1] + v[2]*v[2] + v[3]*v[3];
        #pragma unroll
        for (int s = 32; s; s >>= 1) ss += __shfl_xor(ss, s);
        const float rn = 1.0f / sqrtf(ss);

        floatx4 zn;
        zn[0] = v[0]*rn; zn[1] = v[1]*rn; zn[2] = v[2]*rn; zn[3] = v[3]*rn;
        *(floatx4*)(zf + (size_t)n * DIM + lane * 4) = zn;
        ushortx4 zp;
        zp[0] = f2bf(zn[0]); zp[1] = f2bf(zn[1]);
        zp[2] = f2bf(zn[2]); zp[3] = f2bf(zn[3]);
        *(ushortx4*)(zb + (size_t)n * DIM + lane * 4) = zp;

        if (n < BATCH) {
            float d0 = 0.f, d1 = 0.f;
            if (lane < 50) {
                d0 = dist[(size_t)n * NCLS + 2 * lane];
                d1 = dist[(size_t)n * NCLS + 2 * lane + 1];
            }
            const unsigned long long m0 = __ballot(d0 > 0.5f);
            const unsigned long long m1 = __ballot(d1 > 0.5f);
            if (lane == 0) {
                const int l = m0 ? 2 * __builtin_ctzll(m0)
                                 : 2 * __builtin_ctzll(m1) + 1;
                lab[n] = l;
                lab[n + BATCH] = l;
            }
        }
    }
}

// ---------------------------------------------------------------------------
// K2 (fused): blocks [0,NPAIR) = den MFMA tiles; [NPAIR,NWORK) = class sums.
//     den: 128x128 tile, BK=32 double-buffered LDS (38 KB -> 4 blocks/CU,
//     whole 928-block grid co-resident in ~one round).
//     LDS swizzle: row-major [128][32] shorts; 16B slot s of row r holds
//     global chunk g = s ^ ((r>>1)&3)  (read side applies the same XOR).
// ---------------------------------------------------------------------------
__global__ __launch_bounds__(256, 4) void work_kernel(const __hip_bfloat16* __restrict__ zbp,
                                                      const float* __restrict__ zf,
                                                      const int* __restrict__ lab,
                                                      float* __restrict__ den_part,
                                                      float* __restrict__ csum_part)
{
    __shared__ short tA[2][128 * 32];    // 2 x 8 KB
    __shared__ short tB[2][128 * 32];    // 2 x 8 KB
    __shared__ float red_rs[2][128];
    __shared__ float red_cs[2][128];
    __shared__ float cred[4][DIM];       // csum reduction

    const int t = threadIdx.x;
    const int lane = t & 63, wv = t >> 6;

    if (blockIdx.x >= NPAIR) {
        // ---------------- csum path ----------------
        const int b = blockIdx.x - NPAIR;          // 0..399
        const int c = b % NCLS;
        const int s = b / NCLS;
        const int m0 = s * 1024 + wv * 256;

        floatx4 acc = {0.f, 0.f, 0.f, 0.f};
        #pragma unroll
        for (int g = 0; g < 4; ++g) {
            const int m = m0 + g * 64 + lane;
            unsigned long long mask = __ballot(lab[m] == c);
            while (mask) {
                const int bit = __builtin_ctzll(mask);
                mask &= mask - 1;
                const int mm = m0 + g * 64 + bit;
                acc += *(const floatx4*)(zf + (size_t)mm * DIM + lane * 4);
            }
        }
        *(floatx4*)&cred[wv][lane * 4] = acc;
        __syncthreads();
        if (t < DIM)
            csum_part[((size_t)s * NCLS + c) * DIM + t] =
                cred[0][t] + cred[1][t] + cred[2][t] + cred[3][t];
        return;
    }

    // ---------------- den path ----------------
    int p = blockIdx.x;
    int bi = 0;
    while (p >= NTILE - bi) { p -= NTILE - bi; ++bi; }
    const int bj = bi + p;

    const int wy = wv >> 1, wx = wv & 1;
    const int lr = lane & 15;
    const int lg = lane >> 4;            // 0..3  (16B chunk of the K=32 slab)
    const int sr = lane >> 2;            // 0..15 row-in-q for staging
    const int ss = lane & 3;             // LDS slot for staging

    const short* z = (const short*)zbp;
    const int row0 = bi * 128;
    const int col0 = bj * 128;

    floatx4 acc[4][4] = {};

    auto STAGE = [&](int kt, int b) {
        #pragma unroll
        for (int qi = 0; qi < 2; ++qi) {
            const int q = wv * 2 + qi;               // 0..7, 1 KB each (16 rows)
            const int r = q * 16 + sr;
            const int g = ss ^ ((r >> 1) & 3);       // global chunk for this slot
            gload_lds16(z + (size_t)(row0 + r) * DIM + kt * 32 + g * 8,
                        (char*)tA[b] + q * 1024);
            gload_lds16(z + (size_t)(col0 + r) * DIM + kt * 32 + g * 8,
                        (char*)tB[b] + q * 1024);
        }
    };
    auto COMPUTE = [&](int b) {
        short8 a[4], bb[4];
        #pragma unroll
        for (int i = 0; i < 4; ++i) {
            const int row = wy * 64 + i * 16 + lr;
            const int sl  = lg ^ ((row >> 1) & 3);
            a[i] = *(const short8*)((const char*)tA[b] + row * 64 + sl * 16);
        }
        #pragma unroll
        for (int j = 0; j < 4; ++j) {
            const int col = wx * 64 + j * 16 + lr;
            const int sl  = lg ^ ((col >> 1) & 3);
            bb[j] = *(const short8*)((const char*)tB[b] + col * 64 + sl * 16);
        }
        #pragma unroll
        for (int i = 0; i < 4; ++i)
            #pragma unroll
            for (int j = 0; j < 4; ++j)
                acc[i][j] = __builtin_amdgcn_mfma_f32_16x16x32_bf16(a[i], bb[j], acc[i][j], 0, 0, 0);
    };

    STAGE(0, 0);
    __syncthreads();
    int cur = 0;
    #pragma unroll
    for (int kt = 0; kt < 8; ++kt) {
        if (kt < 7) STAGE(kt + 1, cur ^ 1);
        COMPUTE(cur);
        __syncthreads();
        cur ^= 1;
    }

    // ---- epilogue: e = off-diag exp(sim); row sums + col sums
    float rs[4][4] = {};
    float cs[4]    = {};
    #pragma unroll
    for (int i = 0; i < 4; ++i) {
        #pragma unroll
        for (int j = 0; j < 4; ++j) {
            const int gcol = col0 + wx * 64 + j * 16 + lr;
            #pragma unroll
            for (int r = 0; r < 4; ++r) {
                const int grow = row0 + wy * 64 + i * 16 + lg * 4 + r;
                const float e = (grow == gcol) ? 0.0f : __expf(acc[i][j][r]);
                rs[i][r] += e;
                cs[j]    += e;
            }
        }
    }
    #pragma unroll
    for (int i = 0; i < 4; ++i)
        #pragma unroll
        for (int r = 0; r < 4; ++r) {
            float v = rs[i][r];
            v += __shfl_xor(v, 1); v += __shfl_xor(v, 2);
            v += __shfl_xor(v, 4); v += __shfl_xor(v, 8);
            rs[i][r] = v;
        }
    if (lr == 0)
        #pragma unroll
        for (int i = 0; i < 4; ++i)
            #pragma unroll
            for (int r = 0; r < 4; ++r)
                red_rs[wx][wy * 64 + i * 16 + lg * 4 + r] = rs[i][r];

    #pragma unroll
    for (int j = 0; j < 4; ++j) {
        float v = cs[j];
        v += __shfl_xor(v, 16); v += __shfl_xor(v, 32);
        cs[j] = v;
    }
    if (lane < 16)
        #pragma unroll
        for (int j = 0; j < 4; ++j)
            red_cs[wy][wx * 64 + j * 16 + lr] = cs[j];

    __syncthreads();
    if (t < 128) {
        den_part[(size_t)bj * N_TOT + row0 + t] = red_rs[0][t] + red_rs[1][t];
        if (bi != bj)
            den_part[(size_t)bi * N_TOT + col0 + t] = red_cs[0][t] + red_cs[1][t];
    }
}

// ---------------------------------------------------------------------------
// K3: per-row finalize + last-block final reduce (deterministic order).
//     nom = zf[n].csum[lab[n]] - 1; den = sum of 32 partials.
// ---------------------------------------------------------------------------
__global__ __launch_bounds__(256) void final_kernel(const float* __restrict__ zf,
                                                    const int* __restrict__ lab,
                                                    const float* __restrict__ csum_part,
                                                    const float* __restrict__ den_part,
                                                    float* __restrict__ partial,
                                                    int* __restrict__ counter,
                                                    float* __restrict__ out)
{
    const int t = threadIdx.x;
    const int lane = t & 63, wv = t >> 6;

    float bsum = 0.0f;
    #pragma unroll
    for (int it = 0; it < 2; ++it) {
        const int n = blockIdx.x * 8 + it * 4 + wv;
        const int c = lab[n];

        const floatx4 zv = *(const floatx4*)(zf + (size_t)n * DIM + lane * 4);
        floatx4 sv = {0.f, 0.f, 0.f, 0.f};
        #pragma unroll
        for (int s = 0; s < NSLC; ++s)
            sv += *(const floatx4*)(csum_part + ((size_t)s * NCLS + c) * DIM + lane * 4);

        float pd = zv[0]*sv[0] + zv[1]*sv[1] + zv[2]*sv[2] + zv[3]*sv[3];
        float dd = (lane < 32) ? den_part[(size_t)lane * N_TOT + n] : 0.0f;
        #pragma unroll
        for (int sh = 32; sh; sh >>= 1) {
            pd += __shfl_xor(pd, sh);
            dd += __shfl_xor(dd, sh);
        }
        bsum += (pd - 1.0f) / dd;
    }

    __shared__ float w[4];
    __shared__ int amlast;
    if (lane == 0) w[wv] = bsum;
    __syncthreads();
    if (t == 0) {
        partial[blockIdx.x] = w[0] + w[1] + w[2] + w[3];
        __threadfence();
        amlast = (atomicAdd(counter, 1) == (int)gridDim.x - 1);
    }
    __syncthreads();
    if (amlast) {
        __threadfence();
        float s = partial[t] + partial[t + 256];
        #pragma unroll
        for (int sh = 32; sh; sh >>= 1) s += __shfl_xor(s, sh);
        if (lane == 0) w[wv] = s;
        __syncthreads();
        if (t == 0)
            out[0] = (w[0] + w[1] + w[2] + w[3]) / (float)N_TOT;
    }
}

// ---------------------------------------------------------------------------
extern "C" void kernel_launch(void* const* d_in, const int* in_sizes, int n_in,
                              void* d_out, int out_size, void* d_ws, size_t ws_size,
                              hipStream_t stream)
{
    const float* z_i  = (const float*)d_in[0];
    const float* z_j  = (const float*)d_in[1];
    // d_in[2] (z_n) unused by the reference
    const float* dist = (const float*)d_in[3];

    char* ws = (char*)d_ws;
    unsigned short* zb = (unsigned short*)ws;                                   // 2 MB
    float* zf        = (float*)(ws + 2u * 1024 * 1024);                         // 4 MB
    int*   lab       = (int*)  (ws + 6u * 1024 * 1024);                         // 16 KB
    float* csum_part = (float*)(ws + 6u * 1024 * 1024 + 16 * 1024);             // 400 KB
    float* den_part  = (float*)(ws + 6u * 1024 * 1024 + 416 * 1024);            // 512 KB
    float* partial   = (float*)(ws + 6u * 1024 * 1024 + 928 * 1024);            // 2 KB
    int*   counter   = (int*)  (ws + 6u * 1024 * 1024 + 930 * 1024);            // 4 B

    float* out = (float*)d_out;

    hipLaunchKernelGGL(prep_kernel, dim3(512), dim3(256), 0, stream,
                       z_i, z_j, dist, zb, zf, lab, counter);
    hipLaunchKernelGGL(work_kernel, dim3(NWORK), dim3(256), 0, stream,
                       (const __hip_bfloat16*)zb, zf, lab, den_part, csum_part);
    hipLaunchKernelGGL(final_kernel, dim3(N_TOT / 8), dim3(256), 0, stream,
                       zf, lab, csum_part, den_part, partial, counter, out);
}